// Round 4
// baseline (59.278 us; speedup 1.0000x reference)
//
#include <hip/hip_runtime.h>

#define CIN 16
#define COUT 32
#define NB 8
#define HW 4096
#define PPW 66                 // padded image width
#define PPA (66 * 66)          // padded pixels per image
#define KF 160                 // features per pixel: 16ch * 10 (silu, T1..T8, zero)

typedef short bf16x8 __attribute__((ext_vector_type(8)));
typedef float f32x4 __attribute__((ext_vector_type(4)));

__device__ inline unsigned short f2bf(float f) {
    unsigned u = __builtin_bit_cast(unsigned, f);
    u += 0x7FFFu + ((u >> 16) & 1u);            // RNE
    return (unsigned short)(u >> 16);
}
__device__ inline unsigned pk(float a, float b) {
    return (unsigned)f2bf(a) | ((unsigned)f2bf(b) << 16);
}

#define FEAT_N (16 * PPA)                 // 69696 feature threads
#define FB ((FEAT_N + 255) / 256)         // 273 blocks
#define WF_N (9 * COUT * KF)              // 46080 weight elems
#define WB ((WF_N + 255) / 256)           // 180 blocks

// ---------- Fused prep: features (blocks <FB) + weight fold (blocks >=FB) ----------
__global__ __launch_bounds__(256) void kan_prep(const float* __restrict__ x,
                                                const float* __restrict__ w,
                                                const float* __restrict__ c,
                                                unsigned short* __restrict__ g2,
                                                unsigned short* __restrict__ wf2) {
    if (blockIdx.x < FB) {
        const int t = blockIdx.x * 256 + threadIdx.x;
        if (t >= FEAT_N) return;
        const int b  = t / PPA;
        const int pp = t - b * PPA;
        const int py = pp / PPW;
        const int px = pp - py * PPW;

        unsigned rw[KF / 2];
        const bool interior = (py >= 1) & (py <= 64) & (px >= 1) & (px <= 64);
        if (interior) {
            const int pix = (py - 1) * 64 + (px - 1);
#pragma unroll
            for (int i = 0; i < CIN; ++i) {
                const float v  = x[((size_t)(b * CIN + i)) * HW + pix];
                const float p  = __expf(-v);
                const float p2 = p * p;
                const float s  = v * __builtin_amdgcn_rcpf(1.f + p);           // silu
                const float u  = (1.f - p2) * __builtin_amdgcn_rcpf(1.f + p2); // tanh
                const float u2 = 2.f * u;
                const float t1 = u;
                const float t2 = u2 * u - 1.f;
                const float t3 = u2 * t2 - t1;
                const float t4 = u2 * t3 - t2;
                const float t5 = u2 * t4 - t3;
                const float t6 = u2 * t5 - t4;
                const float t7 = u2 * t6 - t5;
                const float t8 = u2 * t7 - t6;
                rw[i * 5 + 0] = pk(s, t1);
                rw[i * 5 + 1] = pk(t2, t3);
                rw[i * 5 + 2] = pk(t4, t5);
                rw[i * 5 + 3] = pk(t6, t7);
                rw[i * 5 + 4] = (unsigned)f2bf(t8);   // hi half 0 (pad feature)
            }
        } else {
#pragma unroll
            for (int j = 0; j < KF / 2; ++j) rw[j] = 0u;
        }
        uint4* dst = (uint4*)(g2 + (size_t)t * KF);
#pragma unroll
        for (int q = 0; q < KF / 8; ++q)
            dst[q] = make_uint4(rw[4 * q], rw[4 * q + 1], rw[4 * q + 2], rw[4 * q + 3]);
    } else {
        const int t = (blockIdx.x - FB) * 256 + threadIdx.x;
        if (t >= WF_N) return;
        const int f = t % KF;
        const int o = (t / KF) % COUT;
        const int k = t / (KF * COUT);
        const int i = f / 10, n = f % 10;
        float val = 0.f;
        if (n != 9) {
            const float wv = w[(size_t)(i * COUT + o) * 9 + k];
            val = (n == 0) ? wv : wv * c[((size_t)(i * COUT + o) * 9 + k) * NB + (n - 1)];
        }
        wf2[t] = f2bf(val);
    }
}

// ---------- MFMA GEMM: no LDS, no barriers; weights straight from L1/L2 ----------
// Block = 4 waves = one image row (b,y); wave wv owns 16 pixels x0=wv*16, all 32 cout.
__global__ __launch_bounds__(256) void kan_gemm(const unsigned short* __restrict__ g2,
                                                const unsigned short* __restrict__ wf2,
                                                float* __restrict__ out) {
    const int bid = blockIdx.x;
    const int blk = ((bid & 7) << 7) | (bid >> 3);   // XCD swizzle: 8 chunks x 128 rows
    const int b   = blk >> 6;
    const int y   = blk & 63;
    const int tid = threadIdx.x;
    const int l   = tid & 63;
    const int wv  = tid >> 6;
    const int col = l & 15;              // A row (cout) / B col (pixel)
    const int quad = l >> 4;             // k-group
    const int x0  = wv * 16;

    f32x4 acc0 = {0.f, 0.f, 0.f, 0.f};
    f32x4 acc1 = {0.f, 0.f, 0.f, 0.f};

#pragma unroll
    for (int shift = 0; shift < 9; ++shift) {
        const int dy = shift / 3 - 1, dx = shift % 3 - 1;
        const int pp = b * PPA + (y + 1 + dy) * PPW + (x0 + col + 1 + dx);
        const unsigned short* bb = g2  + (size_t)pp * KF + quad * 8;
        const unsigned short* ap = wf2 + ((size_t)shift * COUT + col) * KF + quad * 8;
#pragma unroll
        for (int st = 0; st < 5; ++st) {
            const bf16x8 bf = *(const bf16x8*)(bb + st * 32);
            const bf16x8 a0 = *(const bf16x8*)(ap + st * 32);
            const bf16x8 a1 = *(const bf16x8*)(ap + (size_t)16 * KF + st * 32);
            acc0 = __builtin_amdgcn_mfma_f32_16x16x32_bf16(a0, bf, acc0, 0, 0, 0);
            acc1 = __builtin_amdgcn_mfma_f32_16x16x32_bf16(a1, bf, acc1, 0, 0, 0);
        }
    }

    float* op = out + (size_t)b * COUT * HW + y * 64 + x0 + col;
#pragma unroll
    for (int r = 0; r < 4; ++r) {
        op[(size_t)(quad * 4 + r) * HW]      = acc0[r];
        op[(size_t)(quad * 4 + r + 16) * HW] = acc1[r];
    }
}

extern "C" void kernel_launch(void* const* d_in, const int* in_sizes, int n_in,
                              void* d_out, int out_size, void* d_ws, size_t ws_size,
                              hipStream_t stream) {
    const float* x = (const float*)d_in[0];
    const float* w = (const float*)d_in[1];
    const float* c = (const float*)d_in[2];
    float* out = (float*)d_out;

    unsigned short* g2  = (unsigned short*)d_ws;                       // 16*4356*160 bf16
    unsigned short* wf2 = (unsigned short*)((char*)d_ws + (size_t)16 * PPA * KF * 2);

    kan_prep<<<FB + WB, 256, 0, stream>>>(x, w, c, g2, wf2);
    kan_gemm<<<1024, 256, 0, stream>>>(g2, wf2, out);
}

// Round 5
// 42.083 us; speedup vs baseline: 1.4086x; 1.4086x over previous
//
#include <hip/hip_runtime.h>

#define CIN 16
#define COUT 32
#define NB 8
#define HW 4096
#define PPW 66                 // padded image width
#define PPA (66 * 66)          // padded pixels per image
#define KF 160                 // features per pixel: 16ch * 10 (silu, T1..T8, zero)

typedef short bf16x8 __attribute__((ext_vector_type(8)));
typedef float f32x4 __attribute__((ext_vector_type(4)));

__device__ inline unsigned short f2bf(float f) {
    unsigned u = __builtin_bit_cast(unsigned, f);
    u += 0x7FFFu + ((u >> 16) & 1u);            // RNE
    return (unsigned short)(u >> 16);
}
__device__ inline unsigned pk(float a, float b) {
    return (unsigned)f2bf(a) | ((unsigned)f2bf(b) << 16);
}

#define FEAT_N (16 * PPA)                 // 69696 feature threads
#define FB ((FEAT_N + 255) / 256)         // 273 blocks
#define WF_N (9 * COUT * KF)              // 46080 weight elems
#define WB ((WF_N + 255) / 256)           // 180 blocks

// ---------- Fused prep: features (blocks <FB) + weight fold (blocks >=FB) ----------
__global__ __launch_bounds__(256) void kan_prep(const float* __restrict__ x,
                                                const float* __restrict__ w,
                                                const float* __restrict__ c,
                                                unsigned short* __restrict__ g2,
                                                unsigned short* __restrict__ wf2) {
    if (blockIdx.x < FB) {
        const int t = blockIdx.x * 256 + threadIdx.x;
        if (t >= FEAT_N) return;
        const int b  = t / PPA;
        const int pp = t - b * PPA;
        const int py = pp / PPW;
        const int px = pp - py * PPW;

        unsigned rw[KF / 2];
        const bool interior = (py >= 1) & (py <= 64) & (px >= 1) & (px <= 64);
        if (interior) {
            const int pix = (py - 1) * 64 + (px - 1);
#pragma unroll
            for (int i = 0; i < CIN; ++i) {
                const float v  = x[((size_t)(b * CIN + i)) * HW + pix];
                const float p  = __expf(-v);
                const float p2 = p * p;
                const float s  = v * __builtin_amdgcn_rcpf(1.f + p);           // silu
                const float u  = (1.f - p2) * __builtin_amdgcn_rcpf(1.f + p2); // tanh
                const float u2 = 2.f * u;
                const float t1 = u;
                const float t2 = u2 * u - 1.f;
                const float t3 = u2 * t2 - t1;
                const float t4 = u2 * t3 - t2;
                const float t5 = u2 * t4 - t3;
                const float t6 = u2 * t5 - t4;
                const float t7 = u2 * t6 - t5;
                const float t8 = u2 * t7 - t6;
                rw[i * 5 + 0] = pk(s, t1);
                rw[i * 5 + 1] = pk(t2, t3);
                rw[i * 5 + 2] = pk(t4, t5);
                rw[i * 5 + 3] = pk(t6, t7);
                rw[i * 5 + 4] = (unsigned)f2bf(t8);   // hi half 0 (pad feature)
            }
        } else {
#pragma unroll
            for (int j = 0; j < KF / 2; ++j) rw[j] = 0u;
        }
        uint4* dst = (uint4*)(g2 + (size_t)t * KF);
#pragma unroll
        for (int q = 0; q < KF / 8; ++q)
            dst[q] = make_uint4(rw[4 * q], rw[4 * q + 1], rw[4 * q + 2], rw[4 * q + 3]);
    } else {
        const int t = (blockIdx.x - FB) * 256 + threadIdx.x;
        if (t >= WF_N) return;
        const int f = t % KF;
        const int o = (t / KF) % COUT;
        const int k = t / (KF * COUT);
        const int i = f / 10, n = f % 10;
        float val = 0.f;
        if (n != 9) {
            const float wv = w[(size_t)(i * COUT + o) * 9 + k];
            val = (n == 0) ? wv : wv * c[((size_t)(i * COUT + o) * 9 + k) * NB + (n - 1)];
        }
        wf2[t] = f2bf(val);
    }
}

// ---------- MFMA GEMM: 2-phase LDS weight staging, 3 barriers total ----------
// Block = 512 thr = 8 waves = 2 output rows; wave wv: row y0+(wv>>2), pixels x0=(wv&3)*16.
// LDS holds 5 shifts of Wf (32x160 each) per phase; A from LDS, B gathered from L2.
#define SH0 5                              // shifts in phase 0
#define LDSE (SH0 * COUT * KF)             // 25600 bf16 = 51.2 KB

__global__ __launch_bounds__(512, 4) void kan_gemm(const unsigned short* __restrict__ g2,
                                                   const unsigned short* __restrict__ wf2,
                                                   float* __restrict__ out) {
    __shared__ unsigned short ldsA[LDSE];

    const int bid = blockIdx.x;
    const int blk = ((bid & 7) << 6) | (bid >> 3);   // XCD swizzle: 8 chunks x 64
    const int b   = blk >> 5;
    const int y   = ((blk & 31) << 1) + ((threadIdx.x >> 6) >> 2);
    const int tid = threadIdx.x;
    const int l   = tid & 63;
    const int col = l & 15;              // A row (cout) / B col (pixel)
    const int quad = l >> 4;             // k-group
    const int x0  = ((tid >> 6) & 3) * 16;

    f32x4 acc0 = {0.f, 0.f, 0.f, 0.f};
    f32x4 acc1 = {0.f, 0.f, 0.f, 0.f};

#pragma unroll
    for (int phase = 0; phase < 2; ++phase) {
        const int s0 = phase ? SH0 : 0;
        const int ns = phase ? (9 - SH0) : SH0;
        const int nchunk = ns * COUT * KF / 8;       // 16B chunks to stage

        if (phase) __syncthreads();                  // readers of phase-0 done
        for (int ch = tid; ch < nchunk; ch += 512)   // linear, fully coalesced
            *(uint4*)&ldsA[ch * 8] = *(const uint4*)&wf2[(size_t)s0 * COUT * KF + ch * 8];
        __syncthreads();

#pragma unroll
        for (int ss = 0; ss < SH0; ++ss) {
            if (ss >= ns) break;
            const int shift = s0 + ss;
            const int dy = shift / 3 - 1, dx = shift % 3 - 1;
            const int pp = b * PPA + (y + 1 + dy) * PPW + (x0 + col + 1 + dx);
            const unsigned short* bb = g2 + (size_t)pp * KF + quad * 8;
            const unsigned short* ap = &ldsA[(ss * COUT + col) * KF + quad * 8];
#pragma unroll
            for (int st = 0; st < 5; ++st) {
                const bf16x8 bf = *(const bf16x8*)(bb + st * 32);
                const bf16x8 a0 = *(const bf16x8*)(ap + st * 32);
                const bf16x8 a1 = *(const bf16x8*)(ap + 16 * KF + st * 32);
                acc0 = __builtin_amdgcn_mfma_f32_16x16x32_bf16(a0, bf, acc0, 0, 0, 0);
                acc1 = __builtin_amdgcn_mfma_f32_16x16x32_bf16(a1, bf, acc1, 0, 0, 0);
            }
        }
    }

    float* op = out + (size_t)b * COUT * HW + y * 64 + x0 + col;
#pragma unroll
    for (int r = 0; r < 4; ++r) {
        op[(size_t)(quad * 4 + r) * HW]      = acc0[r];
        op[(size_t)(quad * 4 + r + 16) * HW] = acc1[r];
    }
}

extern "C" void kernel_launch(void* const* d_in, const int* in_sizes, int n_in,
                              void* d_out, int out_size, void* d_ws, size_t ws_size,
                              hipStream_t stream) {
    const float* x = (const float*)d_in[0];
    const float* w = (const float*)d_in[1];
    const float* c = (const float*)d_in[2];
    float* out = (float*)d_out;

    unsigned short* g2  = (unsigned short*)d_ws;                       // 16*4356*160 bf16
    unsigned short* wf2 = (unsigned short*)((char*)d_ws + (size_t)16 * PPA * KF * 2);

    kan_prep<<<FB + WB, 256, 0, stream>>>(x, w, c, g2, wf2);
    kan_gemm<<<512, 512, 0, stream>>>(g2, wf2, out);
}

// Round 6
// 41.212 us; speedup vs baseline: 1.4384x; 1.0211x over previous
//
#include <hip/hip_runtime.h>

#define CIN 16
#define COUT 32
#define NB 8
#define HW 4096
#define PPW 66                 // padded image width
#define PPA (66 * 66)          // padded pixels per image
#define KF 160                 // features per pixel: 16ch * 10 (silu, T1..T8, zero)

typedef short bf16x8 __attribute__((ext_vector_type(8)));
typedef float f32x4 __attribute__((ext_vector_type(4)));

__device__ inline unsigned short f2bf(float f) {
    unsigned u = __builtin_bit_cast(unsigned, f);
    u += 0x7FFFu + ((u >> 16) & 1u);            // RNE
    return (unsigned short)(u >> 16);
}
__device__ inline unsigned pk(float a, float b) {
    return (unsigned)f2bf(a) | ((unsigned)f2bf(b) << 16);
}

#define FEAT_N (16 * PPA)                 // 69696 feature threads
#define FB ((FEAT_N + 255) / 256)         // 273 blocks
#define WF_N (9 * COUT * KF)              // 46080 weight elems (= 90 frags * 64 lanes * 8)
#define WB ((WF_N + 255) / 256)           // 180 blocks

// ---------- Fused prep: features (blocks <FB) + fragment-linear weight fold ----------
// wfl layout: frag = (shift*5 + st)*2 + f  (f: 0 = couts 0-15, 1 = couts 16-31)
//             wfl[frag*512 + lane*8 + e] = Wf[shift][o = f*16 + (lane&15)]
//                                            [kel = st*32 + (lane>>4)*8 + e]
// so the gemm A-read is ldsA + frag*1024B + lane*16B  (linear, conflict-free).
__global__ __launch_bounds__(256) void kan_prep(const float* __restrict__ x,
                                                const float* __restrict__ w,
                                                const float* __restrict__ c,
                                                unsigned short* __restrict__ g2,
                                                unsigned short* __restrict__ wfl) {
    if (blockIdx.x < FB) {
        const int t = blockIdx.x * 256 + threadIdx.x;
        if (t >= FEAT_N) return;
        const int b  = t / PPA;
        const int pp = t - b * PPA;
        const int py = pp / PPW;
        const int px = pp - py * PPW;

        unsigned rw[KF / 2];
        const bool interior = (py >= 1) & (py <= 64) & (px >= 1) & (px <= 64);
        if (interior) {
            const int pix = (py - 1) * 64 + (px - 1);
#pragma unroll
            for (int i = 0; i < CIN; ++i) {
                const float v  = x[((size_t)(b * CIN + i)) * HW + pix];
                const float p  = __expf(-v);
                const float p2 = p * p;
                const float s  = v * __builtin_amdgcn_rcpf(1.f + p);           // silu
                const float u  = (1.f - p2) * __builtin_amdgcn_rcpf(1.f + p2); // tanh
                const float u2 = 2.f * u;
                const float t1 = u;
                const float t2 = u2 * u - 1.f;
                const float t3 = u2 * t2 - t1;
                const float t4 = u2 * t3 - t2;
                const float t5 = u2 * t4 - t3;
                const float t6 = u2 * t5 - t4;
                const float t7 = u2 * t6 - t5;
                const float t8 = u2 * t7 - t6;
                rw[i * 5 + 0] = pk(s, t1);
                rw[i * 5 + 1] = pk(t2, t3);
                rw[i * 5 + 2] = pk(t4, t5);
                rw[i * 5 + 3] = pk(t6, t7);
                rw[i * 5 + 4] = (unsigned)f2bf(t8);   // hi half 0 (pad feature)
            }
        } else {
#pragma unroll
            for (int j = 0; j < KF / 2; ++j) rw[j] = 0u;
        }
        uint4* dst = (uint4*)(g2 + (size_t)t * KF);
#pragma unroll
        for (int q = 0; q < KF / 8; ++q)
            dst[q] = make_uint4(rw[4 * q], rw[4 * q + 1], rw[4 * q + 2], rw[4 * q + 3]);
    } else {
        const int t = (blockIdx.x - FB) * 256 + threadIdx.x;
        if (t >= WF_N) return;
        const int e    = t & 7;
        const int lane = (t >> 3) & 63;
        const int frag = t >> 9;              // 0..89
        const int shift = frag / 10;
        const int r     = frag % 10;
        const int st    = r >> 1;
        const int f     = r & 1;
        const int o     = f * 16 + (lane & 15);
        const int kel   = st * 32 + (lane >> 4) * 8 + e;
        const int i     = kel / 10, n = kel % 10;
        float val = 0.f;
        if (n != 9) {
            const float wv = w[(size_t)(i * COUT + o) * 9 + shift];
            val = (n == 0) ? wv : wv * c[((size_t)(i * COUT + o) * 9 + shift) * NB + (n - 1)];
        }
        wfl[t] = f2bf(val);
    }
}

// ---------- MFMA GEMM: fragment-linear LDS weights (conflict-free), 2-phase staging ----------
// Block = 512 thr = 8 waves = 2 output rows; wave wv: row y0+(wv>>2), pixels x0=(wv&3)*16.
#define P0_FRAGS 50                        // shifts 0-4: 50 frags * 512 elems
#define P1_FRAGS 40                        // shifts 5-8
#define LDSE (P0_FRAGS * 512)              // 25600 bf16 = 51.2 KB

__global__ __launch_bounds__(512, 4) void kan_gemm(const unsigned short* __restrict__ g2,
                                                   const unsigned short* __restrict__ wfl,
                                                   float* __restrict__ out) {
    __shared__ unsigned short ldsA[LDSE];

    const int bid = blockIdx.x;
    const int blk = ((bid & 7) << 6) | (bid >> 3);   // XCD swizzle: 8 chunks x 64
    const int b   = blk >> 5;
    const int tid = threadIdx.x;
    const int l   = tid & 63;
    const int y   = ((blk & 31) << 1) + ((tid >> 6) >> 2);
    const int col = l & 15;              // B col (pixel) / A cout-within-frag
    const int quad = l >> 4;             // k-group
    const int x0  = ((tid >> 6) & 3) * 16;

    const unsigned short* abase = ldsA + l * 8;   // lane-linear A reads

    f32x4 acc0 = {0.f, 0.f, 0.f, 0.f};
    f32x4 acc1 = {0.f, 0.f, 0.f, 0.f};

    // ---- phase 0: shifts 0-4 ----
    for (int ch = tid; ch < P0_FRAGS * 64; ch += 512)     // 3200 x 16B linear copy
        *(uint4*)&ldsA[ch * 8] = *(const uint4*)&wfl[ch * 8];
    __syncthreads();

#pragma unroll
    for (int ss = 0; ss < 5; ++ss) {
        const int dy = ss / 3 - 1, dx = ss % 3 - 1;
        const int pp = b * PPA + (y + 1 + dy) * PPW + (x0 + col + 1 + dx);
        const unsigned short* bb = g2 + (size_t)pp * KF + quad * 8;
#pragma unroll
        for (int st = 0; st < 5; ++st) {
            const bf16x8 bf = *(const bf16x8*)(bb + st * 32);
            const bf16x8 a0 = *(const bf16x8*)(abase + (ss * 10 + st * 2) * 512);
            const bf16x8 a1 = *(const bf16x8*)(abase + (ss * 10 + st * 2 + 1) * 512);
            acc0 = __builtin_amdgcn_mfma_f32_16x16x32_bf16(a0, bf, acc0, 0, 0, 0);
            acc1 = __builtin_amdgcn_mfma_f32_16x16x32_bf16(a1, bf, acc1, 0, 0, 0);
        }
    }
    __syncthreads();

    // ---- phase 1: shifts 5-8 ----
    for (int ch = tid; ch < P1_FRAGS * 64; ch += 512)     // 2560 x 16B
        *(uint4*)&ldsA[ch * 8] = *(const uint4*)&wfl[(size_t)P0_FRAGS * 512 + ch * 8];
    __syncthreads();

#pragma unroll
    for (int ss = 0; ss < 4; ++ss) {
        const int shift = 5 + ss;
        const int dy = shift / 3 - 1, dx = shift % 3 - 1;
        const int pp = b * PPA + (y + 1 + dy) * PPW + (x0 + col + 1 + dx);
        const unsigned short* bb = g2 + (size_t)pp * KF + quad * 8;
#pragma unroll
        for (int st = 0; st < 5; ++st) {
            const bf16x8 bf = *(const bf16x8*)(bb + st * 32);
            const bf16x8 a0 = *(const bf16x8*)(abase + (ss * 10 + st * 2) * 512);
            const bf16x8 a1 = *(const bf16x8*)(abase + (ss * 10 + st * 2 + 1) * 512);
            acc0 = __builtin_amdgcn_mfma_f32_16x16x32_bf16(a0, bf, acc0, 0, 0, 0);
            acc1 = __builtin_amdgcn_mfma_f32_16x16x32_bf16(a1, bf, acc1, 0, 0, 0);
        }
    }

    float* op = out + (size_t)b * COUT * HW + y * 64 + x0 + col;
#pragma unroll
    for (int r = 0; r < 4; ++r) {
        op[(size_t)(quad * 4 + r) * HW]      = acc0[r];
        op[(size_t)(quad * 4 + r + 16) * HW] = acc1[r];
    }
}

extern "C" void kernel_launch(void* const* d_in, const int* in_sizes, int n_in,
                              void* d_out, int out_size, void* d_ws, size_t ws_size,
                              hipStream_t stream) {
    const float* x = (const float*)d_in[0];
    const float* w = (const float*)d_in[1];
    const float* c = (const float*)d_in[2];
    float* out = (float*)d_out;

    unsigned short* g2  = (unsigned short*)d_ws;                       // 16*4356*160 bf16
    unsigned short* wfl = (unsigned short*)((char*)d_ws + (size_t)16 * PPA * KF * 2);

    kan_prep<<<FB + WB, 256, 0, stream>>>(x, w, c, g2, wfl);
    kan_gemm<<<512, 512, 0, stream>>>(g2, wfl, out);
}